// Round 7
// baseline (151.934 us; speedup 1.0000x reference)
//
#include <hip/hip_runtime.h>
#include <math.h>
#include <stdint.h>

#define NB 8
#define SEQ 1024
#define DMODEL 512
#define NH 8
#define HD 64
#define R_TOT (NB * SEQ)   // 8192 rows

typedef __attribute__((ext_vector_type(8))) short bf16x8;
typedef __attribute__((ext_vector_type(4))) float f32x4;

__device__ __forceinline__ short f2b(float x) {
    uint32_t u = __float_as_uint(x);
    u += 0x7FFF + ((u >> 16) & 1);          // round-to-nearest-even
    return (short)(u >> 16);
}
__device__ __forceinline__ float b2f(short s) {
    return __uint_as_float(((uint32_t)(uint16_t)s) << 16);
}
__device__ __forceinline__ uint32_t cvtpk_bf16(float lo, float hi) {
    uint32_t r;
    asm("v_cvt_pk_bf16_f32 %0, %1, %2" : "=v"(r) : "v"(lo), "v"(hi));
    return r;
}

#define GLD_LDS16(g, l)                                                        \
    __builtin_amdgcn_global_load_lds(                                          \
        (const __attribute__((address_space(1))) uint32_t*)(g),                \
        (__attribute__((address_space(3))) uint32_t*)(l), 16, 0, 0)

// ============ GEMM: C[M,N] = act((A[M,K] @ B[N,K]^T + bias)*oscale) ============
// tile 128x64, BK=64 (16 MFMA per barrier), 4 waves 2x2, dbuf LDS, XOR-swizzled.
// B always fp32 (reg-staged + cvt_pk). AFP32: A fp32 reg-staged / A bf16 gload_lds.
// PAIR=1: blockIdx.z selects operand set (q/k merge). PAIR=0: z batches by strides.
#define GBM 128
#define GBN 64
#define GBK 64

template<int AFP32, int PAIR>
__global__ __launch_bounds__(256)
void gemm7(const void* __restrict__ Ap, const float* __restrict__ Bp,
           const float* __restrict__ bias, short* __restrict__ Cp,
           const void* __restrict__ Ap2, const float* __restrict__ Bp2,
           short* __restrict__ Cp2,
           int M, int N, int K, int relu, float os1, float os2,
           long sAb, long sBb, long sCb)
{
    __shared__ short As[2][GBM * GBK];   // [128][64] bf16, rows 128B, XOR-swizzled
    __shared__ short Bs[2][GBN * GBK];   // [64][64]  bf16, rows 128B, XOR-swizzled
    const int tid = threadIdx.x;
    const int l   = tid & 63, w = tid >> 6;
    const int l15 = l & 15,  l4 = l >> 4;
    const int wrow = w >> 1, wcol = w & 1;
    const int m0 = blockIdx.y * GBM, n0 = blockIdx.x * GBN;
    const int z  = blockIdx.z;

    const void*  Aab;
    const float* Bm;
    short*       C;
    float        oscale;
    if (PAIR) {
        Aab = z ? Ap2 : Ap;  Bm = z ? Bp2 : Bp;  C = z ? Cp2 : Cp;
        oscale = z ? os2 : os1;
    } else {
        Aab = (const char*)Ap + (long)z * sAb * (AFP32 ? 4 : 2);
        Bm  = Bp + (long)z * sBb;
        C   = Cp + (long)z * sCb;
        oscale = os1;
    }

    f32x4 acc[4][2] = {};
    const int nsteps = K / GBK;          // 8

    // B fp32 staging: 4 thr/row, 16 floats each
    const int brow = tid >> 2, bq = tid & 3;
    const int swB  = (brow & 7) << 4;
    float4 bv[4];
    auto loadB = [&](int t) {
        const float* bsrc = Bm + (size_t)(n0 + brow) * K + t * GBK + bq * 16;
        bv[0] = ((const float4*)bsrc)[0]; bv[1] = ((const float4*)bsrc)[1];
        bv[2] = ((const float4*)bsrc)[2]; bv[3] = ((const float4*)bsrc)[3];
    };
    auto writeB = [&](int buf) {
        char* dst = (char*)&Bs[buf][brow * GBK];
        uint4 u0 = {cvtpk_bf16(bv[0].x,bv[0].y), cvtpk_bf16(bv[0].z,bv[0].w),
                    cvtpk_bf16(bv[1].x,bv[1].y), cvtpk_bf16(bv[1].z,bv[1].w)};
        uint4 u1 = {cvtpk_bf16(bv[2].x,bv[2].y), cvtpk_bf16(bv[2].z,bv[2].w),
                    cvtpk_bf16(bv[3].x,bv[3].y), cvtpk_bf16(bv[3].z,bv[3].w)};
        *(uint4*)(dst + ((bq * 32 +  0) ^ swB)) = u0;
        *(uint4*)(dst + ((bq * 32 + 16) ^ swB)) = u1;
    };

    // A staging
    const int arow = tid >> 1, ahalf = tid & 1;     // fp32: 2 thr/row, 32 floats
    const int swA  = (arow & 7) << 4;
    float4 av[8];
    auto loadA32 = [&](int t) {
        const float* asrc = (const float*)Aab + (size_t)(m0 + arow) * K + t * GBK + ahalf * 32;
        #pragma unroll
        for (int i = 0; i < 8; ++i) av[i] = ((const float4*)asrc)[i];
    };
    auto writeA32 = [&](int buf) {
        char* dst = (char*)&As[buf][arow * GBK];
        #pragma unroll
        for (int u = 0; u < 4; ++u) {
            uint4 uu = {cvtpk_bf16(av[2*u].x,  av[2*u].y),  cvtpk_bf16(av[2*u].z,  av[2*u].w),
                        cvtpk_bf16(av[2*u+1].x,av[2*u+1].y),cvtpk_bf16(av[2*u+1].z,av[2*u+1].w)};
            *(uint4*)(dst + ((ahalf * 64 + u * 16) ^ swA)) = uu;
        }
    };
    // bf16 A via gload_lds: 4 chunks/thread, pre-swizzled source (rule #21)
    auto stageA16 = [&](int t, int buf) {
        const short* A = (const short*)Aab;
        #pragma unroll
        for (int j = 0; j < 4; ++j) {
            int ch  = tid + j * 256;
            int row = ch >> 3;
            int so  = (((ch & 7) * 16) ^ ((row & 7) << 4)) >> 1;
            GLD_LDS16(A + (size_t)(m0 + row) * K + t * GBK + so, &As[buf][ch * 8]);
        }
    };

    // prologue: stage step 0 into buf 0
    if (AFP32) { loadA32(0); writeA32(0); } else { stageA16(0, 0); }
    loadB(0); writeB(0);
    __syncthreads();

    for (int t = 0; t < nsteps; ++t) {
        const int cur = t & 1;
        const bool more = (t + 1 < nsteps);
        if (more) {                      // issue next-step loads early
            if (AFP32) loadA32(t + 1); else stageA16(t + 1, cur ^ 1);
            loadB(t + 1);
        }
        #pragma unroll
        for (int kk = 0; kk < 2; ++kk) {
            bf16x8 af[4], bfr[2];
            #pragma unroll
            for (int mi = 0; mi < 4; ++mi) {
                int row = wrow * 64 + mi * 16 + l15;
                af[mi] = *(const bf16x8*)((char*)&As[cur][row * GBK] +
                                          ((kk * 64 + l4 * 16) ^ ((row & 7) << 4)));
            }
            #pragma unroll
            for (int ni = 0; ni < 2; ++ni) {
                int row = wcol * 32 + ni * 16 + l15;
                bfr[ni] = *(const bf16x8*)((char*)&Bs[cur][row * GBK] +
                                           ((kk * 64 + l4 * 16) ^ ((row & 7) << 4)));
            }
            #pragma unroll
            for (int mi = 0; mi < 4; ++mi)
                #pragma unroll
                for (int ni = 0; ni < 2; ++ni)
                    acc[mi][ni] = __builtin_amdgcn_mfma_f32_16x16x32_bf16(af[mi], bfr[ni], acc[mi][ni], 0, 0, 0);
        }
        if (more) {                      // write next step to other buffer
            if (AFP32) writeA32(cur ^ 1);
            writeB(cur ^ 1);
        }
        __syncthreads();                 // drains vmcnt+lgkm: next tile resident
    }

    #pragma unroll
    for (int mi = 0; mi < 4; ++mi) {
        #pragma unroll
        for (int ni = 0; ni < 2; ++ni) {
            int col = n0 + wcol * 32 + ni * 16 + l15;
            float bb = bias ? bias[col] : 0.0f;
            #pragma unroll
            for (int r = 0; r < 4; ++r) {
                int row = m0 + wrow * 64 + mi * 16 + l4 * 4 + r;
                float vv = (acc[mi][ni][r] + bb) * oscale;
                if (relu) vv = fmaxf(vv, 0.0f);
                C[(size_t)row * N + col] = f2b(vv);
            }
        }
    }
}

// ============ swapped-QK^T flash attention, log2 softmax, sum-via-MFMA ============
// grid (SEQ/64, NH, NB), 4 waves; wave w owns q-rows blk*64 + w*16 + (l&15)
// kp PRE-SCALED by (1/sqrt(512))*log2(e).
__global__ __launch_bounds__(256, 4)
void attn_mfma5(const short* __restrict__ qp, const short* __restrict__ kp,
                const short* __restrict__ vt, const int* __restrict__ mask,
                short* __restrict__ attn)
{
    __shared__ short Kb[2][64 * 64];             // K tile  [k-row][d], swizzled rows
    __shared__ short Vb[2][64 * 64];             // Vt tile [d-row][k], swizzled rows
    __shared__ __align__(16) char Ps[4 * 2048];  // per-wave P[16q][64k] bf16, swizzled

    const int tid = threadIdx.x;
    const int l   = tid & 63, w = tid >> 6;
    const int l15 = l & 15,  l4 = l >> 4;
    const int h   = blockIdx.y, b = blockIdx.z;
    const int qrow = blockIdx.x * 64 + w * 16 + l15;
    const size_t baseqk = ((size_t)b * SEQ) * DMODEL + h * HD;
    const size_t basev  = ((size_t)b * DMODEL + h * HD) * SEQ;

    const int ch0 = tid, ch1 = tid + 256;
    const int r0 = ch0 >> 3, r1 = ch1 >> 3;
    const int so0 = (((ch0 & 7) * 16) ^ ((r0 & 7) << 4)) >> 1;   // pre-swizzled src
    const int so1 = (((ch1 & 7) * 16) ^ ((r1 & 7) << 4)) >> 1;
    const short* kph = kp + baseqk;
    const short* vth = vt + basev;
    const int*   mrow = mask + b * SEQ;

#define STAGE(t, bufi) do {                                                          \
        GLD_LDS16(kph + (size_t)((t) * 64 + r0) * DMODEL + so0, &Kb[bufi][ch0 * 8]); \
        GLD_LDS16(kph + (size_t)((t) * 64 + r1) * DMODEL + so1, &Kb[bufi][ch1 * 8]); \
        GLD_LDS16(vth + (size_t)r0 * SEQ + (t) * 64 + so0,      &Vb[bufi][ch0 * 8]); \
        GLD_LDS16(vth + (size_t)r1 * SEQ + (t) * 64 + so1,      &Vb[bufi][ch1 * 8]); \
    } while (0)

    bf16x8 qf0, qf1;
    {
        const short* qr = qp + baseqk + (size_t)qrow * DMODEL + l4 * 8;
        qf0 = *(const bf16x8*)qr;
        qf1 = *(const bf16x8*)(qr + 32);
    }
    const bf16x8 ones = {0x3F80, 0x3F80, 0x3F80, 0x3F80, 0x3F80, 0x3F80, 0x3F80, 0x3F80};

    STAGE(0, 0);
    __syncthreads();   // vmcnt(0) drain: tile 0 resident

    float m_ = -1.0e30f;
    f32x4 oacc[4] = {};                          // O^T[d][q]: d = db*16 + l4*4 + r, q = l15
    f32x4 osum = {};                             // row-sum accumulator (all 4 regs equal)
    char* myPs = Ps + w * 2048;
    const int swp = (l15 & 7) << 4;

    for (int t = 0; t < 16; ++t) {
        const int cur = t & 1;
        if (t < 15) STAGE(t + 1, cur ^ 1);       // prefetch overlaps compute

        // ---- S^T[k][q] = K·Q^T from LDS ----
        f32x4 s[4];
        __builtin_amdgcn_s_setprio(1);
        #pragma unroll
        for (int c = 0; c < 4; ++c) {
            int r = c * 16 + l15;
            const short* kb = &Kb[cur][r * 64];
            int o0 = ((l4 * 16) ^ ((r & 7) << 4)) >> 1;
            int o1 = ((64 + l4 * 16) ^ ((r & 7) << 4)) >> 1;
            bf16x8 kf0 = *(const bf16x8*)(kb + o0);
            bf16x8 kf1 = *(const bf16x8*)(kb + o1);
            f32x4 zz = {};
            zz = __builtin_amdgcn_mfma_f32_16x16x32_bf16(kf0, qf0, zz, 0, 0, 0);
            zz = __builtin_amdgcn_mfma_f32_16x16x32_bf16(kf1, qf1, zz, 0, 0, 0);
            s[c] = zz;
        }
        __builtin_amdgcn_s_setprio(0);

        // ---- mask (k = t*64 + c*16 + l4*4 + r) ----
        #pragma unroll
        for (int c = 0; c < 4; ++c) {
            int4 mi = *(const int4*)&mrow[t * 64 + c * 16 + l4 * 4];
            s[c][0] = mi.x ? -1.0e30f : s[c][0];
            s[c][1] = mi.y ? -1.0e30f : s[c][1];
            s[c][2] = mi.z ? -1.0e30f : s[c][2];
            s[c][3] = mi.w ? -1.0e30f : s[c][3];
        }

        // ---- online softmax (exp2 domain), wave-uniform defer-max ----
        float x0 = fmaxf(fmaxf(s[0][0], s[0][1]), fmaxf(s[0][2], s[0][3]));
        float x1 = fmaxf(fmaxf(s[1][0], s[1][1]), fmaxf(s[1][2], s[1][3]));
        float x2 = fmaxf(fmaxf(s[2][0], s[2][1]), fmaxf(s[2][2], s[2][3]));
        float x3 = fmaxf(fmaxf(s[3][0], s[3][1]), fmaxf(s[3][2], s[3][3]));
        float pm = fmaxf(fmaxf(x0, x1), fmaxf(x2, x3));
        pm = fmaxf(pm, __shfl_xor(pm, 16));
        pm = fmaxf(pm, __shfl_xor(pm, 32));
        if (!__all(pm <= m_ + 8.0f)) {
            float mnew = fmaxf(m_, pm);
            float al   = exp2f(m_ - mnew);
            osum[0] *= al; osum[1] *= al; osum[2] *= al; osum[3] *= al;
            #pragma unroll
            for (int db = 0; db < 4; ++db) {
                oacc[db][0] *= al; oacc[db][1] *= al;
                oacc[db][2] *= al; oacc[db][3] *= al;
            }
            m_ = mnew;
        }
        float p[16];
        #pragma unroll
        for (int c = 0; c < 4; ++c)
            #pragma unroll
            for (int r = 0; r < 4; ++r)
                p[c * 4 + r] = exp2f(s[c][r] - m_);

        // ---- P pack + exchange via wave-private swizzled LDS ----
        #pragma unroll
        for (int c = 0; c < 4; ++c) {
            uint2 u;
            u.x = cvtpk_bf16(p[c * 4 + 0], p[c * 4 + 1]);
            u.y = cvtpk_bf16(p[c * 4 + 2], p[c * 4 + 3]);
            *(uint2*)(myPs + ((l15 * 128 + c * 32 + l4 * 8) ^ swp)) = u;
        }
        bf16x8 pf0 = *(const bf16x8*)(myPs + ((l15 * 128 +  0 + l4 * 16) ^ swp));
        bf16x8 pf1 = *(const bf16x8*)(myPs + ((l15 * 128 + 64 + l4 * 16) ^ swp));

        // ---- O^T += Vt·P^T ; row-sum via ones-MFMA (replaces VALU reduction) ----
        __builtin_amdgcn_s_setprio(1);
        osum = __builtin_amdgcn_mfma_f32_16x16x32_bf16(ones, pf0, osum, 0, 0, 0);
        osum = __builtin_amdgcn_mfma_f32_16x16x32_bf16(ones, pf1, osum, 0, 0, 0);
        #pragma unroll
        for (int db = 0; db < 4; ++db) {
            int d = db * 16 + l15;
            const short* vb = &Vb[cur][d * 64];
            int o0 = ((l4 * 16) ^ ((d & 7) << 4)) >> 1;
            int o1 = ((64 + l4 * 16) ^ ((d & 7) << 4)) >> 1;
            bf16x8 vf0 = *(const bf16x8*)(vb + o0);
            bf16x8 vf1 = *(const bf16x8*)(vb + o1);
            oacc[db] = __builtin_amdgcn_mfma_f32_16x16x32_bf16(vf0, pf0, oacc[db], 0, 0, 0);
            oacc[db] = __builtin_amdgcn_mfma_f32_16x16x32_bf16(vf1, pf1, oacc[db], 0, 0, 0);
        }
        __builtin_amdgcn_s_setprio(0);
        __syncthreads();   // tile t+1 landed + closes buf[cur] reads
    }
#undef STAGE

    float inv = (m_ > -1.0e29f) ? 1.0f / osum[0] : 0.0f;   // all-masked row -> 0
    #pragma unroll
    for (int db = 0; db < 4; ++db) {
        short4 o;
        o.x = f2b(oacc[db][0] * inv);
        o.y = f2b(oacc[db][1] * inv);
        o.z = f2b(oacc[db][2] * inv);
        o.w = f2b(oacc[db][3] * inv);
        *(short4*)(attn + baseqk + (size_t)qrow * DMODEL + db * 16 + l4 * 4) = o;
    }
}

// ============ fused add + LayerNorm (bf16 in, bf16 or fp32 out) ============
__global__ __launch_bounds__(256)
void add_ln_b(const short* __restrict__ A, const short* __restrict__ Bv,
              const float* __restrict__ g, const float* __restrict__ beta,
              short* __restrict__ outb, float* __restrict__ outf)
{
    const int row = blockIdx.x;
    const int tid = threadIdx.x;
    const size_t off = (size_t)row * DMODEL;
    short2 a2 = *(const short2*)&A[off + tid * 2];
    short2 c2 = *(const short2*)&Bv[off + tid * 2];
    float x0 = b2f(a2.x) + b2f(c2.x);
    float x1 = b2f(a2.y) + b2f(c2.y);
    float s  = x0 + x1;
    float sq = x0 * x0 + x1 * x1;
    #pragma unroll
    for (int o = 1; o < 64; o <<= 1) {
        s  += __shfl_xor(s,  o);
        sq += __shfl_xor(sq, o);
    }
    __shared__ float ls[4], lq[4];
    const int w = tid >> 6;
    if ((tid & 63) == 0) { ls[w] = s; lq[w] = sq; }
    __syncthreads();
    s  = ls[0] + ls[1] + ls[2] + ls[3];
    sq = lq[0] + lq[1] + lq[2] + lq[3];
    const float mean = s * (1.0f / DMODEL);
    const float var  = sq * (1.0f / DMODEL) - mean * mean;
    const float rs   = rsqrtf(var + 1e-5f);
    const int c0 = tid * 2, c1 = tid * 2 + 1;
    float y0 = (x0 - mean) * rs * g[c0] + beta[c0];
    float y1 = (x1 - mean) * rs * g[c1] + beta[c1];
    if (outb) {
        short2 o; o.x = f2b(y0); o.y = f2b(y1);
        *(short2*)&outb[off + tid * 2] = o;
    } else {
        float2 o; o.x = y0; o.y = y1;
        *(float2*)&outf[off + tid * 2] = o;
    }
}

// ============ launch ============
extern "C" void kernel_launch(void* const* d_in, const int* in_sizes, int n_in,
                              void* d_out, int out_size, void* d_ws, size_t ws_size,
                              hipStream_t stream)
{
    const float* q    = (const float*)d_in[0];
    const float* k    = (const float*)d_in[1];
    const float* v    = (const float*)d_in[2];
    const int*   mask = (const int*)  d_in[3];
    const float* Wq   = (const float*)d_in[4];
    const float* Wk   = (const float*)d_in[5];
    const float* Wv   = (const float*)d_in[6];
    const float* Wo   = (const float*)d_in[7];
    const float* bo   = (const float*)d_in[8];
    const float* g1   = (const float*)d_in[9];
    const float* b1   = (const float*)d_in[10];
    const float* g2   = (const float*)d_in[11];
    const float* bt2  = (const float*)d_in[12];
    float* out = (float*)d_out;

    short* ws = (short*)d_ws;
    const size_t SLOT = (size_t)R_TOT * DMODEL;
    short* qpb = ws;
    short* kpb = qpb + SLOT;
    short* vtb = kpb + SLOT;     // vt[b][dmodel][SEQ]
    short* at  = vtb + SLOT;
    short* y   = at + SLOT;
    short* z   = y + SLOT;

    // kp pre-scaled by (1/sqrt(512)) * log2(e) for exp2-domain softmax
    const float kscale = 0.06375871530f;

    // merged q-proj (z=0) + k-proj (z=1)
    dim3 gqk(DMODEL / GBN, R_TOT / GBM, 2);   // (8, 64, 2)
    gemm7<1, 1><<<gqk, 256, 0, stream>>>(q, Wq, nullptr, qpb, k, Wk, kpb,
                                         R_TOT, DMODEL, DMODEL, 0, 1.0f, kscale,
                                         0, 0, 0);
    // vt[b] = Wv (512x512) @ v_b^T -> [DMODEL][SEQ]
    dim3 gv(SEQ / GBN, DMODEL / GBM, NB);     // (16, 4, 8)
    gemm7<1, 0><<<gv, 256, 0, stream>>>(Wv, v, nullptr, vtb, nullptr, nullptr, nullptr,
                                        DMODEL, SEQ, DMODEL, 0, 1.0f, 0.0f,
                                        0, (long)SEQ * DMODEL, (long)DMODEL * SEQ);

    attn_mfma5<<<dim3(SEQ / 64, NH, NB), 256, 0, stream>>>(qpb, kpb, vtb, mask, at);

    add_ln_b<<<R_TOT, 256, 0, stream>>>(qpb, at, g1, b1, y, nullptr);

    // out-proj: A = y (bf16, gload_lds path), B = Wo fp32, +bias, relu
    dim3 gg(DMODEL / GBN, R_TOT / GBM, 1);    // (8, 64)
    gemm7<0, 0><<<gg, 256, 0, stream>>>(y, Wo, bo, z, nullptr, nullptr, nullptr,
                                        R_TOT, DMODEL, DMODEL, 1, 1.0f, 0.0f,
                                        0, 0, 0);

    add_ln_b<<<R_TOT, 256, 0, stream>>>(y, z, g2, bt2, nullptr, out);
}

// Round 8
// 118.645 us; speedup vs baseline: 1.2806x; 1.2806x over previous
//
#include <hip/hip_runtime.h>
#include <math.h>
#include <stdint.h>

#define NB 8
#define SEQ 1024
#define DMODEL 512
#define NH 8
#define HD 64
#define R_TOT (NB * SEQ)   // 8192 rows

typedef __attribute__((ext_vector_type(8))) short bf16x8;
typedef __attribute__((ext_vector_type(4))) float f32x4;

__device__ __forceinline__ short f2b(float x) {
    uint32_t u = __float_as_uint(x);
    u += 0x7FFF + ((u >> 16) & 1);          // round-to-nearest-even
    return (short)(u >> 16);
}
__device__ __forceinline__ float b2f(short s) {
    return __uint_as_float(((uint32_t)(uint16_t)s) << 16);
}
__device__ __forceinline__ uint32_t cvtpk_bf16(float lo, float hi) {
    uint32_t r;
    asm("v_cvt_pk_bf16_f32 %0, %1, %2" : "=v"(r) : "v"(lo), "v"(hi));
    return r;
}

#define GLD_LDS16(g, l)                                                        \
    __builtin_amdgcn_global_load_lds(                                          \
        (const __attribute__((address_space(1))) uint32_t*)(g),                \
        (__attribute__((address_space(3))) uint32_t*)(l), 16, 0, 0)

// T1: bijective chunked XCD swizzle (nwg % 8 == 0 for all our grids)
__device__ __forceinline__ void xcd_swizzle(int& bx, int& by, int& bz) {
    const int gx = gridDim.x, gy = gridDim.y;
    const int nwg = gx * gy * gridDim.z;
    int id = (blockIdx.z * gy + blockIdx.y) * gx + blockIdx.x;
    int lg = (id & 7) * (nwg >> 3) + (id >> 3);
    bx = lg % gx;
    int tmp = lg / gx;
    by = tmp % gy;
    bz = tmp / gy;
}

// ---------------- merged fp32 -> bf16 convert (q,k,v + 4 weights) ----------------
#define N4B (R_TOT * DMODEL / 4)    // 1048576 float4 per activation tensor
#define N4W (DMODEL * DMODEL / 4)   // 65536 per weight

__global__ __launch_bounds__(256)
void cvt_all(const float* __restrict__ q, const float* __restrict__ k, const float* __restrict__ v,
             const float* __restrict__ wq, const float* __restrict__ wk,
             const float* __restrict__ wv, const float* __restrict__ wo,
             short* dq, short* dk, short* dv, short* dwq, short* dwk, short* dwv, short* dwo)
{
    long i = (long)blockIdx.x * 256 + threadIdx.x;
    const float* s; short* d; long off;
    if (i < (long)N4B)          { s = q;  d = dq;  off = i; }
    else if (i < 2L * N4B)      { s = k;  d = dk;  off = i - N4B; }
    else if (i < 3L * N4B)      { s = v;  d = dv;  off = i - 2L * N4B; }
    else {
        long j = i - 3L * N4B;
        int  w = (int)(j >> 16);
        off = j & (N4W - 1);
        s = (w == 0) ? wq : (w == 1) ? wk : (w == 2) ? wv : wo;
        d = (w == 0) ? dwq : (w == 1) ? dwk : (w == 2) ? dwv : dwo;
    }
    float4 x = ((const float4*)s)[off];
    short4 o;
    o.x = f2b(x.x); o.y = f2b(x.y); o.z = f2b(x.z); o.w = f2b(x.w);
    ((short4*)d)[off] = o;
}

// ============ GEMM: C[M,N] = act((A[M,K] @ B[N,K]^T + bias)*oscale), batched ============
// tile 128x64, BK=64, dbuf XOR-swizzled LDS (conflict-free, R7-verified), both operands
// bf16 via global_load_lds, XCD-swizzled grid. oscale = bz ? os2 : os1.
#define GBM 128
#define GBN 64
#define GBK 64

__global__ __launch_bounds__(256)
void gemm8(const short* __restrict__ Ap, const short* __restrict__ Bp,
           const float* __restrict__ bias, short* __restrict__ Cp,
           int M, int N, int K, int relu, float os1, float os2,
           long sAb, long sBb, long sCb)
{
    __shared__ short As[2][GBM * GBK];   // [128][64] bf16 rows=128B, XOR-swizzled
    __shared__ short Bs[2][GBN * GBK];   // [64][64]
    const int tid = threadIdx.x;
    const int l   = tid & 63, w = tid >> 6;
    const int l15 = l & 15,  l4 = l >> 4;
    const int wrow = w >> 1, wcol = w & 1;

    int bx, by, bz;
    xcd_swizzle(bx, by, bz);
    const int m0 = by * GBM, n0 = bx * GBN;
    const short* A  = Ap + (long)bz * sAb;
    const short* Bm = Bp + (long)bz * sBb;
    short*       C  = Cp + (long)bz * sCb;
    const float oscale = bz ? os2 : os1;

    f32x4 acc[4][2] = {};
    const int nsteps = K / GBK;          // 8

    auto stageA = [&](int t, int buf) {
        #pragma unroll
        for (int j = 0; j < 4; ++j) {
            int ch  = tid + j * 256;
            int row = ch >> 3;
            int so  = (((ch & 7) * 16) ^ ((row & 7) << 4)) >> 1;   // rule-21 pre-swizzle
            GLD_LDS16(A + (size_t)(m0 + row) * K + t * GBK + so, &As[buf][ch * 8]);
        }
    };
    auto stageB = [&](int t, int buf) {
        #pragma unroll
        for (int j = 0; j < 2; ++j) {
            int ch  = tid + j * 256;
            int row = ch >> 3;
            int so  = (((ch & 7) * 16) ^ ((row & 7) << 4)) >> 1;
            GLD_LDS16(Bm + (size_t)(n0 + row) * K + t * GBK + so, &Bs[buf][ch * 8]);
        }
    };

    stageA(0, 0); stageB(0, 0);
    __syncthreads();

    for (int t = 0; t < nsteps; ++t) {
        const int cur = t & 1;
        if (t + 1 < nsteps) { stageA(t + 1, cur ^ 1); stageB(t + 1, cur ^ 1); }
        __builtin_amdgcn_s_setprio(1);
        #pragma unroll
        for (int kk = 0; kk < 2; ++kk) {
            bf16x8 af[4], bfr[2];
            #pragma unroll
            for (int mi = 0; mi < 4; ++mi) {
                int row = wrow * 64 + mi * 16 + l15;
                af[mi] = *(const bf16x8*)((char*)&As[cur][row * GBK] +
                                          ((kk * 64 + l4 * 16) ^ ((row & 7) << 4)));
            }
            #pragma unroll
            for (int ni = 0; ni < 2; ++ni) {
                int row = wcol * 32 + ni * 16 + l15;
                bfr[ni] = *(const bf16x8*)((char*)&Bs[cur][row * GBK] +
                                           ((kk * 64 + l4 * 16) ^ ((row & 7) << 4)));
            }
            #pragma unroll
            for (int mi = 0; mi < 4; ++mi)
                #pragma unroll
                for (int ni = 0; ni < 2; ++ni)
                    acc[mi][ni] = __builtin_amdgcn_mfma_f32_16x16x32_bf16(af[mi], bfr[ni], acc[mi][ni], 0, 0, 0);
        }
        __builtin_amdgcn_s_setprio(0);
        __syncthreads();                 // drains vmcnt: next tile resident
    }

    #pragma unroll
    for (int mi = 0; mi < 4; ++mi) {
        #pragma unroll
        for (int ni = 0; ni < 2; ++ni) {
            int col = n0 + wcol * 32 + ni * 16 + l15;
            float bb = bias ? bias[col] : 0.0f;
            #pragma unroll
            for (int r = 0; r < 4; ++r) {
                int row = m0 + wrow * 64 + mi * 16 + l4 * 4 + r;
                float vv = (acc[mi][ni][r] + bb) * oscale;
                if (relu) vv = fmaxf(vv, 0.0f);
                C[(size_t)row * N + col] = f2b(vv);
            }
        }
    }
}

// ============ swapped-QK^T flash attention, log2 softmax, sum-via-MFMA ============
// grid (SEQ/64, NH, NB) XCD-swizzled; 4 waves; wave w owns q-rows blk*64+w*16+(l&15)
// kp PRE-SCALED by (1/sqrt(512))*log2(e).
__global__ __launch_bounds__(256, 4)
void attn_mfma5(const short* __restrict__ qp, const short* __restrict__ kp,
                const short* __restrict__ vt, const int* __restrict__ mask,
                short* __restrict__ attn)
{
    __shared__ short Kb[2][64 * 64];
    __shared__ short Vb[2][64 * 64];
    __shared__ __align__(16) char Ps[4 * 2048];

    const int tid = threadIdx.x;
    const int l   = tid & 63, w = tid >> 6;
    const int l15 = l & 15,  l4 = l >> 4;
    int qb_, h, b;
    xcd_swizzle(qb_, h, b);
    const int qrow = qb_ * 64 + w * 16 + l15;
    const size_t baseqk = ((size_t)b * SEQ) * DMODEL + h * HD;
    const size_t basev  = ((size_t)b * DMODEL + h * HD) * SEQ;

    const int ch0 = tid, ch1 = tid + 256;
    const int r0 = ch0 >> 3, r1 = ch1 >> 3;
    const int so0 = (((ch0 & 7) * 16) ^ ((r0 & 7) << 4)) >> 1;
    const int so1 = (((ch1 & 7) * 16) ^ ((r1 & 7) << 4)) >> 1;
    const short* kph = kp + baseqk;
    const short* vth = vt + basev;
    const int*   mrow = mask + b * SEQ;

#define STAGE(t, bufi) do {                                                          \
        GLD_LDS16(kph + (size_t)((t) * 64 + r0) * DMODEL + so0, &Kb[bufi][ch0 * 8]); \
        GLD_LDS16(kph + (size_t)((t) * 64 + r1) * DMODEL + so1, &Kb[bufi][ch1 * 8]); \
        GLD_LDS16(vth + (size_t)r0 * SEQ + (t) * 64 + so0,      &Vb[bufi][ch0 * 8]); \
        GLD_LDS16(vth + (size_t)r1 * SEQ + (t) * 64 + so1,      &Vb[bufi][ch1 * 8]); \
    } while (0)

    bf16x8 qf0, qf1;
    {
        const short* qr = qp + baseqk + (size_t)qrow * DMODEL + l4 * 8;
        qf0 = *(const bf16x8*)qr;
        qf1 = *(const bf16x8*)(qr + 32);
    }
    const bf16x8 ones = {0x3F80, 0x3F80, 0x3F80, 0x3F80, 0x3F80, 0x3F80, 0x3F80, 0x3F80};

    STAGE(0, 0);
    __syncthreads();

    float m_ = -1.0e30f;
    f32x4 oacc[4] = {};                          // O^T[d][q]: d = db*16+l4*4+r, q = l15
    f32x4 osum = {};                             // row-sum accumulator
    char* myPs = Ps + w * 2048;
    const int swp = (l15 & 7) << 4;

    for (int t = 0; t < 16; ++t) {
        const int cur = t & 1;
        if (t < 15) STAGE(t + 1, cur ^ 1);

        f32x4 s[4];
        __builtin_amdgcn_s_setprio(1);
        #pragma unroll
        for (int c = 0; c < 4; ++c) {
            int r = c * 16 + l15;
            const short* kb = &Kb[cur][r * 64];
            int o0 = ((l4 * 16) ^ ((r & 7) << 4)) >> 1;
            int o1 = ((64 + l4 * 16) ^ ((r & 7) << 4)) >> 1;
            bf16x8 kf0 = *(const bf16x8*)(kb + o0);
            bf16x8 kf1 = *(const bf16x8*)(kb + o1);
            f32x4 zz = {};
            zz = __builtin_amdgcn_mfma_f32_16x16x32_bf16(kf0, qf0, zz, 0, 0, 0);
            zz = __builtin_amdgcn_mfma_f32_16x16x32_bf16(kf1, qf1, zz, 0, 0, 0);
            s[c] = zz;
        }
        __builtin_amdgcn_s_setprio(0);

        #pragma unroll
        for (int c = 0; c < 4; ++c) {
            int4 mi = *(const int4*)&mrow[t * 64 + c * 16 + l4 * 4];
            s[c][0] = mi.x ? -1.0e30f : s[c][0];
            s[c][1] = mi.y ? -1.0e30f : s[c][1];
            s[c][2] = mi.z ? -1.0e30f : s[c][2];
            s[c][3] = mi.w ? -1.0e30f : s[c][3];
        }

        float x0 = fmaxf(fmaxf(s[0][0], s[0][1]), fmaxf(s[0][2], s[0][3]));
        float x1 = fmaxf(fmaxf(s[1][0], s[1][1]), fmaxf(s[1][2], s[1][3]));
        float x2 = fmaxf(fmaxf(s[2][0], s[2][1]), fmaxf(s[2][2], s[2][3]));
        float x3 = fmaxf(fmaxf(s[3][0], s[3][1]), fmaxf(s[3][2], s[3][3]));
        float pm = fmaxf(fmaxf(x0, x1), fmaxf(x2, x3));
        pm = fmaxf(pm, __shfl_xor(pm, 16));
        pm = fmaxf(pm, __shfl_xor(pm, 32));
        if (!__all(pm <= m_ + 8.0f)) {           // defer-max (T13), wave-uniform
            float mnew = fmaxf(m_, pm);
            float al   = exp2f(m_ - mnew);
            osum[0] *= al; osum[1] *= al; osum[2] *= al; osum[3] *= al;
            #pragma unroll
            for (int db = 0; db < 4; ++db) {
                oacc[db][0] *= al; oacc[db][1] *= al;
                oacc[db][2] *= al; oacc[db][3] *= al;
            }
            m_ = mnew;
        }
        float p[16];
        #pragma unroll
        for (int c = 0; c < 4; ++c)
            #pragma unroll
            for (int r = 0; r < 4; ++r)
                p[c * 4 + r] = exp2f(s[c][r] - m_);

        #pragma unroll
        for (int c = 0; c < 4; ++c) {
            uint2 u;
            u.x = cvtpk_bf16(p[c * 4 + 0], p[c * 4 + 1]);
            u.y = cvtpk_bf16(p[c * 4 + 2], p[c * 4 + 3]);
            *(uint2*)(myPs + ((l15 * 128 + c * 32 + l4 * 8) ^ swp)) = u;
        }
        bf16x8 pf0 = *(const bf16x8*)(myPs + ((l15 * 128 +  0 + l4 * 16) ^ swp));
        bf16x8 pf1 = *(const bf16x8*)(myPs + ((l15 * 128 + 64 + l4 * 16) ^ swp));

        __builtin_amdgcn_s_setprio(1);
        osum = __builtin_amdgcn_mfma_f32_16x16x32_bf16(ones, pf0, osum, 0, 0, 0);
        osum = __builtin_amdgcn_mfma_f32_16x16x32_bf16(ones, pf1, osum, 0, 0, 0);
        #pragma unroll
        for (int db = 0; db < 4; ++db) {
            int d = db * 16 + l15;
            const short* vb = &Vb[cur][d * 64];
            int o0 = ((l4 * 16) ^ ((d & 7) << 4)) >> 1;
            int o1 = ((64 + l4 * 16) ^ ((d & 7) << 4)) >> 1;
            bf16x8 vf0 = *(const bf16x8*)(vb + o0);
            bf16x8 vf1 = *(const bf16x8*)(vb + o1);
            oacc[db] = __builtin_amdgcn_mfma_f32_16x16x32_bf16(vf0, pf0, oacc[db], 0, 0, 0);
            oacc[db] = __builtin_amdgcn_mfma_f32_16x16x32_bf16(vf1, pf1, oacc[db], 0, 0, 0);
        }
        __builtin_amdgcn_s_setprio(0);
        __syncthreads();
    }
#undef STAGE

    float inv = (m_ > -1.0e29f) ? 1.0f / osum[0] : 0.0f;   // all-masked row -> 0
    #pragma unroll
    for (int db = 0; db < 4; ++db) {
        short4 o;
        o.x = f2b(oacc[db][0] * inv);
        o.y = f2b(oacc[db][1] * inv);
        o.z = f2b(oacc[db][2] * inv);
        o.w = f2b(oacc[db][3] * inv);
        *(short4*)(attn + baseqk + (size_t)qrow * DMODEL + db * 16 + l4 * 4) = o;
    }
}

// ============ fused add + LayerNorm (bf16 in, bf16 or fp32 out) ============
__global__ __launch_bounds__(256)
void add_ln_b(const short* __restrict__ A, const short* __restrict__ Bv,
              const float* __restrict__ g, const float* __restrict__ beta,
              short* __restrict__ outb, float* __restrict__ outf)
{
    const int row = blockIdx.x;
    const int tid = threadIdx.x;
    const size_t off = (size_t)row * DMODEL;
    short2 a2 = *(const short2*)&A[off + tid * 2];
    short2 c2 = *(const short2*)&Bv[off + tid * 2];
    float x0 = b2f(a2.x) + b2f(c2.x);
    float x1 = b2f(a2.y) + b2f(c2.y);
    float s  = x0 + x1;
    float sq = x0 * x0 + x1 * x1;
    #pragma unroll
    for (int o = 1; o < 64; o <<= 1) {
        s  += __shfl_xor(s,  o);
        sq += __shfl_xor(sq, o);
    }
    __shared__ float ls[4], lq[4];
    const int w = tid >> 6;
    if ((tid & 63) == 0) { ls[w] = s; lq[w] = sq; }
    __syncthreads();
    s  = ls[0] + ls[1] + ls[2] + ls[3];
    sq = lq[0] + lq[1] + lq[2] + lq[3];
    const float mean = s * (1.0f / DMODEL);
    const float var  = sq * (1.0f / DMODEL) - mean * mean;
    const float rs   = rsqrtf(var + 1e-5f);
    const int c0 = tid * 2, c1 = tid * 2 + 1;
    float y0 = (x0 - mean) * rs * g[c0] + beta[c0];
    float y1 = (x1 - mean) * rs * g[c1] + beta[c1];
    if (outb) {
        short2 o; o.x = f2b(y0); o.y = f2b(y1);
        *(short2*)&outb[off + tid * 2] = o;
    } else {
        float2 o; o.x = y0; o.y = y1;
        *(float2*)&outf[off + tid * 2] = o;
    }
}

// ============ launch ============
extern "C" void kernel_launch(void* const* d_in, const int* in_sizes, int n_in,
                              void* d_out, int out_size, void* d_ws, size_t ws_size,
                              hipStream_t stream)
{
    const float* q    = (const float*)d_in[0];
    const float* k    = (const float*)d_in[1];
    const float* v    = (const float*)d_in[2];
    const int*   mask = (const int*)  d_in[3];
    const float* Wq   = (const float*)d_in[4];
    const float* Wk   = (const float*)d_in[5];
    const float* Wv   = (const float*)d_in[6];
    const float* Wo   = (const float*)d_in[7];
    const float* bo   = (const float*)d_in[8];
    const float* g1   = (const float*)d_in[9];
    const float* b1   = (const float*)d_in[10];
    const float* g2   = (const float*)d_in[11];
    const float* bt2  = (const float*)d_in[12];
    float* out = (float*)d_out;

    short* ws = (short*)d_ws;
    const size_t WSZ  = (size_t)DMODEL * DMODEL;
    const size_t SLOT = (size_t)R_TOT * DMODEL;
    short* wq  = ws;
    short* wk  = ws + WSZ;       // contiguous after wq (merged-qk B stride)
    short* wv  = ws + 2 * WSZ;
    short* wo  = ws + 3 * WSZ;
    short* qb  = ws + 4 * WSZ;
    short* kb  = qb + SLOT;      // contiguous after qb (merged-qk A stride)
    short* vb  = kb + SLOT;
    short* qpb = vb + SLOT;
    short* kpb = qpb + SLOT;     // contiguous after qpb (merged-qk C stride)
    short* vtb = kpb + SLOT;     // vt[b][dmodel][SEQ]
    short* at  = qb;             // qb dead after q/k projection
    short* y   = kb;             // kb dead after q/k projection
    short* z   = vb;             // vb dead after vt GEMM

    const int nCvtBlocks = (3 * N4B + 4 * N4W) / 256;   // 13312
    cvt_all<<<nCvtBlocks, 256, 0, stream>>>(q, k, v, Wq, Wk, Wv, Wo,
                                            qb, kb, vb, wq, wk, wv, wo);

    // kp pre-scaled by (1/sqrt(512)) * log2(e) for exp2-domain softmax
    const float kscale = 0.06375871530f;

    // merged q-proj (bz=0) + k-proj (bz=1) via batch strides
    dim3 gqk(DMODEL / GBN, R_TOT / GBM, 2);   // (8, 64, 2)
    gemm8<<<gqk, 256, 0, stream>>>(qb, wq, nullptr, qpb,
                                   R_TOT, DMODEL, DMODEL, 0, 1.0f, kscale,
                                   (long)SLOT, (long)WSZ, (long)SLOT);
    // vt[b] = Wv @ v_b^T -> [DMODEL][SEQ]
    dim3 gv(SEQ / GBN, DMODEL / GBM, NB);     // (16, 4, 8)
    gemm8<<<gv, 256, 0, stream>>>(wv, vb, nullptr, vtb,
                                  DMODEL, SEQ, DMODEL, 0, 1.0f, 1.0f,
                                  0, (long)SEQ * DMODEL, (long)DMODEL * SEQ);

    attn_mfma5<<<dim3(SEQ / 64, NH, NB), 256, 0, stream>>>(qpb, kpb, vtb, mask, at);

    add_ln_b<<<R_TOT, 256, 0, stream>>>(qpb, at, g1, b1, y, nullptr);

    // out-proj: A = y bf16, B = wo bf16, +bias, relu
    dim3 gg(DMODEL / GBN, R_TOT / GBM, 1);    // (8, 64)
    gemm8<<<gg, 256, 0, stream>>>(y, wo, bo, z,
                                  R_TOT, DMODEL, DMODEL, 1, 1.0f, 1.0f,
                                  0, 0, 0);

    add_ln_b<<<R_TOT, 256, 0, stream>>>(y, z, g2, bt2, nullptr, out);
}

// Round 9
// 105.322 us; speedup vs baseline: 1.4426x; 1.1265x over previous
//
#include <hip/hip_runtime.h>
#include <math.h>
#include <stdint.h>

#define NB 8
#define SEQ 1024
#define DMODEL 512
#define NH 8
#define HD 64
#define R_TOT (NB * SEQ)   // 8192 rows

typedef __attribute__((ext_vector_type(8))) short bf16x8;
typedef __attribute__((ext_vector_type(4))) float f32x4;

__device__ __forceinline__ short f2b(float x) {
    uint32_t u = __float_as_uint(x);
    u += 0x7FFF + ((u >> 16) & 1);          // round-to-nearest-even
    return (short)(u >> 16);
}
__device__ __forceinline__ float b2f(short s) {
    return __uint_as_float(((uint32_t)(uint16_t)s) << 16);
}
__device__ __forceinline__ uint32_t cvtpk_bf16(float lo, float hi) {
    uint32_t r;
    asm("v_cvt_pk_bf16_f32 %0, %1, %2" : "=v"(r) : "v"(lo), "v"(hi));
    return r;
}

#define GLD_LDS16(g, l)                                                        \
    __builtin_amdgcn_global_load_lds(                                          \
        (const __attribute__((address_space(1))) uint32_t*)(g),                \
        (__attribute__((address_space(3))) uint32_t*)(l), 16, 0, 0)

// T1: bijective chunked XCD swizzle for 3D grids with nwg % 8 == 0
__device__ __forceinline__ void xcd_swizzle(int& bx, int& by, int& bz) {
    const int gx = gridDim.x, gy = gridDim.y;
    const int nwg = gx * gy * gridDim.z;
    int id = (blockIdx.z * gy + blockIdx.y) * gx + blockIdx.x;
    int lg = (id & 7) * (nwg >> 3) + (id >> 3);
    bx = lg % gx;
    int tmp = lg / gx;
    by = tmp % gy;
    bz = tmp / gy;
}

// ---------------- merged fp32 -> bf16 convert (q,k,v + 4 weights) ----------------
#define N4B (R_TOT * DMODEL / 4)
#define N4W (DMODEL * DMODEL / 4)

__global__ __launch_bounds__(256)
void cvt_all(const float* __restrict__ q, const float* __restrict__ k, const float* __restrict__ v,
             const float* __restrict__ wq, const float* __restrict__ wk,
             const float* __restrict__ wv, const float* __restrict__ wo,
             short* dq, short* dk, short* dv, short* dwq, short* dwk, short* dwv, short* dwo)
{
    long i = (long)blockIdx.x * 256 + threadIdx.x;
    const float* s; short* d; long off;
    if (i < (long)N4B)          { s = q;  d = dq;  off = i; }
    else if (i < 2L * N4B)      { s = k;  d = dk;  off = i - N4B; }
    else if (i < 3L * N4B)      { s = v;  d = dv;  off = i - 2L * N4B; }
    else {
        long j = i - 3L * N4B;
        int  w = (int)(j >> 16);
        off = j & (N4W - 1);
        s = (w == 0) ? wq : (w == 1) ? wk : (w == 2) ? wv : wo;
        d = (w == 0) ? dwq : (w == 1) ? dwk : (w == 2) ? dwv : dwo;
    }
    float4 x = ((const float4*)s)[off];
    short4 o;
    o.x = f2b(x.x); o.y = f2b(x.y); o.z = f2b(x.z); o.w = f2b(x.w);
    ((short4*)d)[off] = o;
}

// ============ shared GEMM inner: 128x64 tile, BK=64, dbuf swizzled LDS ============
#define GBM 128
#define GBN 64
#define GBK 64

// C[M,N](row=m0..,col=n0..) = act((A[.,K=512] @ B[.,K=512]^T + bias)*oscale)
__device__ __forceinline__ void gemm_core(
    const short* __restrict__ A, const short* __restrict__ Bm,
    const float* __restrict__ bias, short* __restrict__ C,
    int N, int m0, int n0, int relu, float oscale,
    short (*As)[GBM * GBK], short (*Bs)[GBN * GBK])
{
    const int tid = threadIdx.x;
    const int l   = tid & 63, w = tid >> 6;
    const int l15 = l & 15,  l4 = l >> 4;
    const int wrow = w >> 1, wcol = w & 1;
    const int K = 512;

    f32x4 acc[4][2] = {};

    auto stageA = [&](int t, int buf) {
        #pragma unroll
        for (int j = 0; j < 4; ++j) {
            int ch  = tid + j * 256;
            int row = ch >> 3;
            int so  = (((ch & 7) * 16) ^ ((row & 7) << 4)) >> 1;
            GLD_LDS16(A + (size_t)(m0 + row) * K + t * GBK + so, &As[buf][ch * 8]);
        }
    };
    auto stageB = [&](int t, int buf) {
        #pragma unroll
        for (int j = 0; j < 2; ++j) {
            int ch  = tid + j * 256;
            int row = ch >> 3;
            int so  = (((ch & 7) * 16) ^ ((row & 7) << 4)) >> 1;
            GLD_LDS16(Bm + (size_t)(n0 + row) * K + t * GBK + so, &Bs[buf][ch * 8]);
        }
    };

    stageA(0, 0); stageB(0, 0);
    __syncthreads();

    for (int t = 0; t < 8; ++t) {
        const int cur = t & 1;
        if (t + 1 < 8) { stageA(t + 1, cur ^ 1); stageB(t + 1, cur ^ 1); }
        __builtin_amdgcn_s_setprio(1);
        #pragma unroll
        for (int kk = 0; kk < 2; ++kk) {
            bf16x8 af[4], bfr[2];
            #pragma unroll
            for (int mi = 0; mi < 4; ++mi) {
                int row = wrow * 64 + mi * 16 + l15;
                af[mi] = *(const bf16x8*)((char*)&As[cur][row * GBK] +
                                          ((kk * 64 + l4 * 16) ^ ((row & 7) << 4)));
            }
            #pragma unroll
            for (int ni = 0; ni < 2; ++ni) {
                int row = wcol * 32 + ni * 16 + l15;
                bfr[ni] = *(const bf16x8*)((char*)&Bs[cur][row * GBK] +
                                           ((kk * 64 + l4 * 16) ^ ((row & 7) << 4)));
            }
            #pragma unroll
            for (int mi = 0; mi < 4; ++mi)
                #pragma unroll
                for (int ni = 0; ni < 2; ++ni)
                    acc[mi][ni] = __builtin_amdgcn_mfma_f32_16x16x32_bf16(af[mi], bfr[ni], acc[mi][ni], 0, 0, 0);
        }
        __builtin_amdgcn_s_setprio(0);
        __syncthreads();
    }

    #pragma unroll
    for (int mi = 0; mi < 4; ++mi) {
        #pragma unroll
        for (int ni = 0; ni < 2; ++ni) {
            int col = n0 + wcol * 32 + ni * 16 + l15;
            float bb = bias ? bias[col] : 0.0f;
            #pragma unroll
            for (int r = 0; r < 4; ++r) {
                int row = m0 + wrow * 64 + mi * 16 + l4 * 4 + r;
                float vv = (acc[mi][ni][r] + bb) * oscale;
                if (relu) vv = fmaxf(vv, 0.0f);
                C[(size_t)row * N + col] = f2b(vv);
            }
        }
    }
}

// ---- merged projections: q-proj + k-proj (1024 blocks) + vt (512 blocks) ----
// flat 1536-block grid, chunked XCD swizzle, decode into 3 sub-GEMMs.
__global__ __launch_bounds__(256)
void proj3(const short* __restrict__ qb, const short* __restrict__ kb,
           const short* __restrict__ vb, const short* __restrict__ wq,
           const short* __restrict__ wv,
           short* __restrict__ qpb, short* __restrict__ vtb, float kscale)
{
    __shared__ short As[2][GBM * GBK];
    __shared__ short Bs[2][GBN * GBK];
    const size_t WSZ  = (size_t)DMODEL * DMODEL;
    const size_t SLOT = (size_t)R_TOT * DMODEL;

    int id = blockIdx.x;
    int lg = (id & 7) * 192 + (id >> 3);    // 1536/8 = 192 per XCD chunk

    const short *A, *Bm; short* C; int N, m0, n0; float os = 1.0f;
    if (lg < 1024) {                        // q/k projection: C = X @ W^T
        int bz  = lg >> 9;                  // 0=q, 1=k
        int rem = lg & 511;
        m0 = (rem >> 3) * GBM;              // by 0..63
        n0 = (rem & 7) * GBN;               // bx 0..7
        A  = bz ? kb : qb;
        Bm = wq + bz * WSZ;                 // wq, wk contiguous
        C  = qpb + bz * SLOT;               // qpb, kpb contiguous
        N  = DMODEL;
        os = bz ? kscale : 1.0f;
    } else {                                // vt[b] = Wv @ v_b^T
        int r2  = lg - 1024;
        int b   = r2 >> 6;                  // 0..7
        int rem = r2 & 63;
        m0 = (rem >> 4) * GBM;              // by 0..3
        n0 = (rem & 15) * GBN;              // bx 0..15
        A  = wv;
        Bm = vb + (long)b * SEQ * DMODEL;
        C  = vtb + (long)b * DMODEL * SEQ;
        N  = SEQ;
    }
    gemm_core(A, Bm, nullptr, C, N, m0, n0, 0, os, As, Bs);
}

// ---- out-projection (single GEMM) ----
__global__ __launch_bounds__(256)
void outproj(const short* __restrict__ y, const short* __restrict__ wo,
             const float* __restrict__ bias, short* __restrict__ z)
{
    __shared__ short As[2][GBM * GBK];
    __shared__ short Bs[2][GBN * GBK];
    int bx, by, bz;
    xcd_swizzle(bx, by, bz);
    gemm_core(y, wo, bias, z, DMODEL, by * GBM, bx * GBN, 1, 1.0f, As, Bs);
}

// ============ flash attention: QBLK=128, 8 waves, hoisted offsets ============
// grid (8, NH, NB) XCD-swizzled; wave w owns q-rows qb*128 + w*16 + (l&15)
// kp PRE-SCALED by (1/sqrt(512))*log2(e).
__global__ __launch_bounds__(512)
void attn_mfma6(const short* __restrict__ qp, const short* __restrict__ kp,
                const short* __restrict__ vt, const int* __restrict__ mask,
                short* __restrict__ attn)
{
    __shared__ short Kb[2][64 * 64];             // K tile  [k-row][d], swizzled
    __shared__ short Vb[2][64 * 64];             // Vt tile [d-row][k], swizzled
    __shared__ __align__(16) char Ps[8 * 2048];  // per-wave P[16q][64k]
    // LDS = 48KB -> 3 blocks/CU cap (2 resident needed)

    const int tid = threadIdx.x;
    const int l   = tid & 63, w = tid >> 6;      // w 0..7
    const int l15 = l & 15,  l4 = l >> 4;
    int qb_, h, b;
    xcd_swizzle(qb_, h, b);
    const int qrow = qb_ * 128 + w * 16 + l15;
    const size_t baseqk = ((size_t)b * SEQ) * DMODEL + h * HD;
    const size_t basev  = ((size_t)b * DMODEL + h * HD) * SEQ;

    // staging: each thread 1 K-chunk + 1 V-chunk (512 thr x 16B = 8KB each)
    const int ch  = tid;
    const int row = ch >> 3;
    const int so  = ((((ch & 7) * 16) ^ ((row & 7) << 4)) >> 1);
    const short* kph = kp + baseqk;
    const short* vth = vt + basev;
    const int*   mrow = mask + b * SEQ;

#define STAGE(t, bufi) do {                                                        \
        GLD_LDS16(kph + (size_t)((t) * 64 + row) * DMODEL + so, &Kb[bufi][ch * 8]); \
        GLD_LDS16(vth + (size_t)row * SEQ + (t) * 64 + so,      &Vb[bufi][ch * 8]); \
    } while (0)

    // hoisted lane-constant LDS byte offsets:
    // K/V read: row' = blk*16 + l15 -> (row'&7) == (l15&7) for all blk
    const int swk   = (l15 & 7) << 4;
    const int kOff0 = l15 * 128 + ((l4 * 16) ^ swk);
    const int kOff1 = l15 * 128 + ((64 + l4 * 16) ^ swk);
    int pwOff[4];
    #pragma unroll
    for (int c = 0; c < 4; ++c)
        pwOff[c] = (l15 * 128 + c * 32 + l4 * 8) ^ swk;
    const int prOff0 = (l15 * 128 + l4 * 16) ^ swk;
    const int prOff1 = (l15 * 128 + 64 + l4 * 16) ^ swk;

    bf16x8 qf0, qf1;
    {
        const short* qr = qp + baseqk + (size_t)qrow * DMODEL + l4 * 8;
        qf0 = *(const bf16x8*)qr;
        qf1 = *(const bf16x8*)(qr + 32);
    }
    const bf16x8 ones = {0x3F80, 0x3F80, 0x3F80, 0x3F80, 0x3F80, 0x3F80, 0x3F80, 0x3F80};

    STAGE(0, 0);
    __syncthreads();

    float m_ = -1.0e30f;
    f32x4 oacc[4] = {};                          // O^T[d][q]: d = db*16+l4*4+r, q = l15
    f32x4 osum = {};                             // row-sum via ones-MFMA
    char* myPs = Ps + w * 2048;

    #pragma unroll 2
    for (int t = 0; t < 16; ++t) {
        const int cur = t & 1;
        if (t < 15) STAGE(t + 1, cur ^ 1);

        // ---- S^T[k][q] = K.Q^T ----
        f32x4 s[4];
        __builtin_amdgcn_s_setprio(1);
        #pragma unroll
        for (int c = 0; c < 4; ++c) {
            const char* kbase = (const char*)&Kb[cur][0] + c * 2048;
            bf16x8 kf0 = *(const bf16x8*)(kbase + kOff0);
            bf16x8 kf1 = *(const bf16x8*)(kbase + kOff1);
            f32x4 zz = {};
            zz = __builtin_amdgcn_mfma_f32_16x16x32_bf16(kf0, qf0, zz, 0, 0, 0);
            zz = __builtin_amdgcn_mfma_f32_16x16x32_bf16(kf1, qf1, zz, 0, 0, 0);
            s[c] = zz;
        }
        __builtin_amdgcn_s_setprio(0);

        // ---- mask (k = t*64 + c*16 + l4*4 + r) ----
        #pragma unroll
        for (int c = 0; c < 4; ++c) {
            int4 mi = *(const int4*)&mrow[t * 64 + c * 16 + l4 * 4];
            s[c][0] = mi.x ? -1.0e30f : s[c][0];
            s[c][1] = mi.y ? -1.0e30f : s[c][1];
            s[c][2] = mi.z ? -1.0e30f : s[c][2];
            s[c][3] = mi.w ? -1.0e30f : s[c][3];
        }

        // ---- max via v_max3 tree (16 -> 1 in 8 ops) ----
        float a0 = fmaxf(fmaxf(s[0][0], s[0][1]), s[0][2]);
        float a1 = fmaxf(fmaxf(s[0][3], s[1][0]), s[1][1]);
        float a2 = fmaxf(fmaxf(s[1][2], s[1][3]), s[2][0]);
        float a3 = fmaxf(fmaxf(s[2][1], s[2][2]), s[2][3]);
        float a4 = fmaxf(fmaxf(s[3][0], s[3][1]), s[3][2]);
        float pm = fmaxf(fmaxf(fmaxf(a0, a1), a2), fmaxf(fmaxf(a3, a4), s[3][3]));
        pm = fmaxf(pm, __shfl_xor(pm, 16));
        pm = fmaxf(pm, __shfl_xor(pm, 32));
        if (!__all(pm <= m_ + 8.0f)) {           // defer-max (T13), wave-uniform
            float mnew = fmaxf(m_, pm);
            float al   = exp2f(m_ - mnew);
            osum[0] *= al; osum[1] *= al; osum[2] *= al; osum[3] *= al;
            #pragma unroll
            for (int db = 0; db < 4; ++db) {
                oacc[db][0] *= al; oacc[db][1] *= al;
                oacc[db][2] *= al; oacc[db][3] *= al;
            }
            m_ = mnew;
        }
        float p[16];
        #pragma unroll
        for (int c = 0; c < 4; ++c)
            #pragma unroll
            for (int r = 0; r < 4; ++r)
                p[c * 4 + r] = exp2f(s[c][r] - m_);

        // ---- P pack + exchange (wave-private swizzled LDS) ----
        #pragma unroll
        for (int c = 0; c < 4; ++c) {
            uint2 u;
            u.x = cvtpk_bf16(p[c * 4 + 0], p[c * 4 + 1]);
            u.y = cvtpk_bf16(p[c * 4 + 2], p[c * 4 + 3]);
            *(uint2*)(myPs + pwOff[c]) = u;
        }
        bf16x8 pf0 = *(const bf16x8*)(myPs + prOff0);
        bf16x8 pf1 = *(const bf16x8*)(myPs + prOff1);

        // ---- O^T += Vt.P^T ; row-sum via ones-MFMA ----
        __builtin_amdgcn_s_setprio(1);
        osum = __builtin_amdgcn_mfma_f32_16x16x32_bf16(ones, pf0, osum, 0, 0, 0);
        osum = __builtin_amdgcn_mfma_f32_16x16x32_bf16(ones, pf1, osum, 0, 0, 0);
        #pragma unroll
        for (int db = 0; db < 4; ++db) {
            const char* vbase = (const char*)&Vb[cur][0] + db * 2048;
            bf16x8 vf0 = *(const bf16x8*)(vbase + kOff0);
            bf16x8 vf1 = *(const bf16x8*)(vbase + kOff1);
            oacc[db] = __builtin_amdgcn_mfma_f32_16x16x32_bf16(vf0, pf0, oacc[db], 0, 0, 0);
            oacc[db] = __builtin_amdgcn_mfma_f32_16x16x32_bf16(vf1, pf1, oacc[db], 0, 0, 0);
        }
        __builtin_amdgcn_s_setprio(0);
        __syncthreads();
    }
#undef STAGE

    float inv = (m_ > -1.0e29f) ? 1.0f / osum[0] : 0.0f;   // all-masked row -> 0
    #pragma unroll
    for (int db = 0; db < 4; ++db) {
        short4 o;
        o.x = f2b(oacc[db][0] * inv);
        o.y = f2b(oacc[db][1] * inv);
        o.z = f2b(oacc[db][2] * inv);
        o.w = f2b(oacc[db][3] * inv);
        *(short4*)(attn + baseqk + (size_t)qrow * DMODEL + db * 16 + l4 * 4) = o;
    }
}

// ============ fused add + LayerNorm (bf16 in, bf16 or fp32 out) ============
__global__ __launch_bounds__(256)
void add_ln_b(const short* __restrict__ A, const short* __restrict__ Bv,
              const float* __restrict__ g, const float* __restrict__ beta,
              short* __restrict__ outb, float* __restrict__ outf)
{
    const int row = blockIdx.x;
    const int tid = threadIdx.x;
    const size_t off = (size_t)row * DMODEL;
    short2 a2 = *(const short2*)&A[off + tid * 2];
    short2 c2 = *(const short2*)&Bv[off + tid * 2];
    float x0 = b2f(a2.x) + b2f(c2.x);
    float x1 = b2f(a2.y) + b2f(c2.y);
    float s  = x0 + x1;
    float sq = x0 * x0 + x1 * x1;
    #pragma unroll
    for (int o = 1; o < 64; o <<= 1) {
        s  += __shfl_xor(s,  o);
        sq += __shfl_xor(sq, o);
    }
    __shared__ float ls[4], lq[4];
    const int w = tid >> 6;
    if ((tid & 63) == 0) { ls[w] = s; lq[w] = sq; }
    __syncthreads();
    s  = ls[0] + ls[1] + ls[2] + ls[3];
    sq = lq[0] + lq[1] + lq[2] + lq[3];
    const float mean = s * (1.0f / DMODEL);
    const float var  = sq * (1.0f / DMODEL) - mean * mean;
    const float rs   = rsqrtf(var + 1e-5f);
    const int c0 = tid * 2, c1 = tid * 2 + 1;
    float y0 = (x0 - mean) * rs * g[c0] + beta[c0];
    float y1 = (x1 - mean) * rs * g[c1] + beta[c1];
    if (outb) {
        short2 o; o.x = f2b(y0); o.y = f2b(y1);
        *(short2*)&outb[off + tid * 2] = o;
    } else {
        float2 o; o.x = y0; o.y = y1;
        *(float2*)&outf[off + tid * 2] = o;
    }
}

// ============ launch ============
extern "C" void kernel_launch(void* const* d_in, const int* in_sizes, int n_in,
                              void* d_out, int out_size, void* d_ws, size_t ws_size,
                              hipStream_t stream)
{
    const float* q    = (const float*)d_in[0];
    const float* k    = (const float*)d_in[1];
    const float* v    = (const float*)d_in[2];
    const int*   mask = (const int*)  d_in[3];
    const float* Wq   = (const float*)d_in[4];
    const float* Wk   = (const float*)d_in[5];
    const float* Wv   = (const float*)d_in[6];
    const float* Wo   = (const float*)d_in[7];
    const float* bo   = (const float*)d_in[8];
    const float* g1   = (const float*)d_in[9];
    const float* b1   = (const float*)d_in[10];
    const float* g2   = (const float*)d_in[11];
    const float* bt2  = (const float*)d_in[12];
    float* out = (float*)d_out;

    short* ws = (short*)d_ws;
    const size_t WSZ  = (size_t)DMODEL * DMODEL;
    const size_t SLOT = (size_t)R_TOT * DMODEL;
    short* wq  = ws;
    short* wk  = ws + WSZ;       // contiguous after wq
    short* wv  = ws + 2 * WSZ;
    short* wo  = ws + 3 * WSZ;
    short* qb  = ws + 4 * WSZ;
    short* kb  = qb + SLOT;
    short* vb  = kb + SLOT;
    short* qpb = vb + SLOT;
    short* kpb = qpb + SLOT;     // contiguous after qpb
    short* vtb = kpb + SLOT;     // vt[b][dmodel][SEQ]
    short* at  = qb;             // qb dead after projections
    short* y   = kb;             // kb dead after projections
    short* z   = vb;             // vb dead after projections

    const int nCvtBlocks = (3 * N4B + 4 * N4W) / 256;   // 13312
    cvt_all<<<nCvtBlocks, 256, 0, stream>>>(q, k, v, Wq, Wk, Wv, Wo,
                                            qb, kb, vb, wq, wk, wv, wo);

    // kp pre-scaled by (1/sqrt(512)) * log2(e) for exp2-domain softmax
    const float kscale = 0.06375871530f;

    // merged q-proj + k-proj + vt (1536 blocks, internally XCD-swizzled)
    proj3<<<1536, 256, 0, stream>>>(qb, kb, vb, wq, wv, qpb, vtb, kscale);

    attn_mfma6<<<dim3(SEQ / 128, NH, NB), 512, 0, stream>>>(qpb, kpb, vtb, mask, at);

    add_ln_b<<<R_TOT, 256, 0, stream>>>(qpb, at, g1, b1, y, nullptr);

    outproj<<<dim3(DMODEL / GBN, R_TOT / GBM, 1), 256, 0, stream>>>(y, wo, bo, z);

    add_ln_b<<<R_TOT, 256, 0, stream>>>(y, z, g2, bt2, nullptr, out);
}